// Round 1
// baseline (161.338 us; speedup 1.0000x reference)
//
#include <hip/hip_runtime.h>

// Masked embedding gather:
//   idx = x[i]; if (idx % 2 == 0) idx = 0;  out[i, :] = emb[idx, :]
// x: (8, 4096) int32, emb: (50257, 512) fp32, out: (8, 4096, 512) fp32.
//
// R0 change vs previous best: 8 tokens per wave instead of 1.
//  - One coalesced load of 8 token ids per wave (was 8 waves x 1 broadcast
//    load each), broadcast in-register via __shfl.
//  - All 16 gather float4 loads issued before the first store: 8x the
//    memory-level parallelism per wave; compiler staggers s_waitcnt vmcnt(N)
//    so stores drain while later loads are still in flight.
//  - Row reads and writes stay fully coalesced 16 B/lane (2 KiB/row).

#define EMB 512
#define TPW 8   // tokens per wave

__global__ __launch_bounds__(256) void embed_gather_kernel(
    const int* __restrict__ x,
    const float* __restrict__ emb,
    float* __restrict__ out,
    int n_tokens)
{
    const int wid  = (blockIdx.x * blockDim.x + threadIdx.x) >> 6;  // global wave id
    const int lane = threadIdx.x & 63;
    const int tbase = wid * TPW;
    if (tbase >= n_tokens) return;

    if (tbase + TPW <= n_tokens) {
        // ---- fast path: full group of 8 tokens ----
        // lanes 0..7 hold the 8 token ids (other lanes load duplicates of the
        // same 32 B segment -> single memory request)
        int id = x[tbase + (lane & (TPW - 1))];
        id = (id & 1) ? id : 0;                 // even ids -> row 0

        float4 v[TPW][2];
        #pragma unroll
        for (int i = 0; i < TPW; ++i) {
            const int row = __shfl(id, i, 64);  // wave-uniform row index
            const float4* __restrict__ src =
                (const float4*)(emb + (size_t)row * EMB);
            v[i][0] = src[lane];                // 128 float4 per row, 2 per lane
            v[i][1] = src[lane + 64];
        }
        #pragma unroll
        for (int i = 0; i < TPW; ++i) {
            float4* __restrict__ dst =
                (float4*)(out + (size_t)(tbase + i) * EMB);
            dst[lane]      = v[i][0];
            dst[lane + 64] = v[i][1];
        }
    } else {
        // ---- tail path (not taken for n_tokens = 32768) ----
        for (int t = tbase; t < n_tokens; ++t) {
            int id = x[t];
            if ((id & 1) == 0) id = 0;
            const float4* __restrict__ src =
                (const float4*)(emb + (size_t)id * EMB);
            float4* __restrict__ dst = (float4*)(out + (size_t)t * EMB);
            dst[lane]      = src[lane];
            dst[lane + 64] = src[lane + 64];
        }
    }
}

extern "C" void kernel_launch(void* const* d_in, const int* in_sizes, int n_in,
                              void* d_out, int out_size, void* d_ws, size_t ws_size,
                              hipStream_t stream)
{
    const int* x = (const int*)d_in[0];          // (8, 4096) int32
    const float* emb = (const float*)d_in[1];    // (50257, 512) fp32
    float* out = (float*)d_out;                  // (8, 4096, 512) fp32

    const int n_tokens = in_sizes[0];            // 32768
    const int tokens_per_block = (256 / 64) * TPW;  // 4 waves x 8 tokens = 32
    const int blocks = (n_tokens + tokens_per_block - 1) / tokens_per_block;

    embed_gather_kernel<<<blocks, 256, 0, stream>>>(x, emb, out, n_tokens);
}